// Round 2
// baseline (192.624 us; speedup 1.0000x reference)
//
#include <hip/hip_runtime.h>

#define LQg 2048
#define LKg 2048
#define DDg 256
#define NBg 16

typedef unsigned int uint;
typedef __attribute__((ext_vector_type(8))) __bf16 bf16x8;
typedef __attribute__((ext_vector_type(16))) float f32x16;

static __device__ __forceinline__ uint pack2(float a, float b) {
    unsigned short ua = __builtin_bit_cast(unsigned short, (__bf16)a);
    unsigned short ub = __builtin_bit_cast(unsigned short, (__bf16)b);
    return (uint)ua | ((uint)ub << 16);
}

static __device__ __forceinline__ f32x16 mfma32(bf16x8 a, bf16x8 b, f32x16 c) {
    return __builtin_amdgcn_mfma_f32_32x32x16_bf16(a, b, c, 0, 0, 0);
}

// rotation of the 128B V row; depends only on (dv mod 32) -> per-lane constant
static __device__ __forceinline__ int vrot(int dv) {
    return (((dv & 15) * 8) + (((dv >> 2) & 7) * 16)) & 127;
}

// ---- suffix-sum of V over [tile-aligned boundary, 2048) : deterministic 2-stage ----
__global__ void tv_partial_k(const float* __restrict__ V, const int* __restrict__ vlen,
                             float* __restrict__ part) {
    const int c = blockIdx.x, b = blockIdx.y, t = threadIdx.x;
    const int vl = vlen[b];
    int bnd = ((vl + 63) >> 6) << 6;
    if (bnd > LKg) bnd = LKg;
    const int k0 = c * 128, k1 = k0 + 128;
    int lo = k0 > bnd ? k0 : bnd;
    float s = 0.f;
    for (int k = lo; k < k1; ++k) s += V[((size_t)(b * LKg + k)) * DDg + t];
    part[(size_t)(b * 16 + c) * DDg + t] = s;
}

__global__ void tv_reduce_k(const float* __restrict__ part, float* __restrict__ TV) {
    const int b = blockIdx.x, t = threadIdx.x;
    float s = 0.f;
    for (int c = 0; c < 16; ++c) s += part[(size_t)(b * 16 + c) * DDg + t];
    TV[b * DDg + t] = s;
}

// ---- main fused attention ----
__global__ __launch_bounds__(128, 1) void attn_k(
    const float* __restrict__ Qg, const float* __restrict__ Kg,
    const float* __restrict__ Vg, const int* __restrict__ vlen,
    const float* __restrict__ TV, float* __restrict__ Og, int use_tail) {
    __shared__ alignas(16) unsigned char sK[64 * 512];   // [64 k][256 d] bf16, XOR-swizzled
    __shared__ alignas(16) unsigned char sV[256 * 128];  // [256 dv][64 k] bf16, rotated rows

    const int tid = threadIdx.x;
    const int lane = tid & 63;
    const int w = tid >> 6;       // wave id 0/1
    const int lq = lane & 31;     // q (and dv) index within tile
    const int h = lane >> 5;      // lane half
    const int b = blockIdx.x & 15;
    const int qb = blockIdx.x >> 4;
    const int q = qb * 64 + w * 32 + lq;
    const int vl = vlen[b];

    const float SCALE = 0.09016844136f;  // (1/16) * log2(e); softmax done in exp2 domain

    // ---- Q fragments in registers (pre-scaled, bf16) ----
    bf16x8 qf[16];
    {
        const float* qp = Qg + ((size_t)(b * LQg + q)) * DDg + h * 8;
#pragma unroll
        for (int c = 0; c < 16; ++c) {
            float4 a = *(const float4*)(qp + c * 16);
            float4 bb = *(const float4*)(qp + c * 16 + 4);
            uint4 u;
            u.x = pack2(a.x * SCALE, a.y * SCALE);
            u.y = pack2(a.z * SCALE, a.w * SCALE);
            u.z = pack2(bb.x * SCALE, bb.y * SCALE);
            u.w = pack2(bb.z * SCALE, bb.w * SCALE);
            qf[c] = __builtin_bit_cast(bf16x8, u);
        }
    }

    f32x16 acc[8];
#pragma unroll
    for (int i = 0; i < 8; ++i)
#pragma unroll
        for (int j = 0; j < 16; ++j) acc[i][j] = 0.f;

    float m = -1e30f, ell = 0.f;

    const int tt = tid & 63, th = tid >> 6;
    const int swzK = (lq & 7) << 4;
    const int rotv = vrot(lq);

    const int nt = use_tail ? ((vl + 63) >> 6) : (LKg / 64);

    for (int t = 0; t < nt; ++t) {
        const int k0 = t * 64;
        __syncthreads();  // previous iteration's LDS reads done

        // ---- stage K tile: [64][256] f32 -> bf16, XOR-swizzled rows ----
        {
            const float* kp = Kg + ((size_t)(b * LKg + k0)) * DDg;
#pragma unroll
            for (int i = 0; i < 32; ++i) {
                const int row = 2 * i + th;
                const int d4 = tt * 4;
                float4 v = *(const float4*)(kp + (size_t)row * DDg + d4);
                uint2 uu;
                uu.x = pack2(v.x, v.y);
                uu.y = pack2(v.z, v.w);
                const uint off = (uint)(row * 512) + (uint)((d4 * 2) ^ ((row & 7) << 4));
                *(uint2*)(sK + off) = uu;
            }
        }
        // ---- stage V tile transposed: [dv][k] bf16 with in-row rotation ----
        {
            const float* vp = Vg + ((size_t)(b * LKg + k0)) * DDg;
            const int dv4 = tt * 4;
#pragma unroll
            for (int kb = 0; kb < 8; ++kb) {
                const int kbase = th * 32 + kb * 4;
                float4 r0 = *(const float4*)(vp + (size_t)(kbase + 0) * DDg + dv4);
                float4 r1 = *(const float4*)(vp + (size_t)(kbase + 1) * DDg + dv4);
                float4 r2 = *(const float4*)(vp + (size_t)(kbase + 2) * DDg + dv4);
                float4 r3 = *(const float4*)(vp + (size_t)(kbase + 3) * DDg + dv4);
                {
                    const int dv = dv4 + 0;
                    uint2 uu; uu.x = pack2(r0.x, r1.x); uu.y = pack2(r2.x, r3.x);
                    *(uint2*)(sV + (uint)(dv * 128) + (uint)((kbase * 2 + vrot(dv)) & 127)) = uu;
                }
                {
                    const int dv = dv4 + 1;
                    uint2 uu; uu.x = pack2(r0.y, r1.y); uu.y = pack2(r2.y, r3.y);
                    *(uint2*)(sV + (uint)(dv * 128) + (uint)((kbase * 2 + vrot(dv)) & 127)) = uu;
                }
                {
                    const int dv = dv4 + 2;
                    uint2 uu; uu.x = pack2(r0.z, r1.z); uu.y = pack2(r2.z, r3.z);
                    *(uint2*)(sV + (uint)(dv * 128) + (uint)((kbase * 2 + vrot(dv)) & 127)) = uu;
                }
                {
                    const int dv = dv4 + 3;
                    uint2 uu; uu.x = pack2(r0.w, r1.w); uu.y = pack2(r2.w, r3.w);
                    *(uint2*)(sV + (uint)(dv * 128) + (uint)((kbase * 2 + vrot(dv)) & 127)) = uu;
                }
            }
        }
        __syncthreads();

        // ---- QK^T as S^T = mfma(K, Q^T): lane pair (l, l+32) holds P-row for q = lq ----
        f32x16 s0, s1;
#pragma unroll
        for (int j = 0; j < 16; ++j) { s0[j] = 0.f; s1[j] = 0.f; }
#pragma unroll
        for (int c = 0; c < 16; ++c) {
            const int inner = (c * 32 + h * 16) ^ swzK;
            bf16x8 kf0 = *(const bf16x8*)(sK + lq * 512 + inner);
            bf16x8 kf1 = *(const bf16x8*)(sK + (32 + lq) * 512 + inner);
            s0 = mfma32(kf0, qf[c], s0);
            s1 = mfma32(kf1, qf[c], s1);
        }

        // ---- mask (masked score := 0, matching the reference!) ----
        const bool full = (k0 + 64 <= vl);
        if (!full) {
            const int kb0 = k0 + 4 * h;
#pragma unroll
            for (int r = 0; r < 16; ++r) {
                const int key0 = kb0 + (r & 3) + 8 * (r >> 2);
                if (key0 >= vl) s0[r] = 0.f;
                if (key0 + 32 >= vl) s1[r] = 0.f;
            }
        }

        // ---- online softmax; m/ell are PER Q-ROW -> must be identical across the
        //      (lane, lane+32) pair, which jointly holds one row. Pair-reduce mt & rs.
        float mt = s0[0];
#pragma unroll
        for (int r = 1; r < 16; ++r) mt = fmaxf(mt, s0[r]);
#pragma unroll
        for (int r = 0; r < 16; ++r) mt = fmaxf(mt, s1[r]);
        mt = fmaxf(mt, __shfl_xor(mt, 32));   // <- pair-consistent tile max
        if (mt > m + 8.f) {
            const float mn = fmaxf(m, mt);
            const float sf = exp2f(m - mn);
            ell *= sf;
#pragma unroll
            for (int i = 0; i < 8; ++i) acc[i] *= sf;
            m = mn;
        }
        float rs = 0.f;
#pragma unroll
        for (int r = 0; r < 16; ++r) { s0[r] = exp2f(s0[r] - m); rs += s0[r]; }
#pragma unroll
        for (int r = 0; r < 16; ++r) { s1[r] = exp2f(s1[r] - m); rs += s1[r]; }
        rs += __shfl_xor(rs, 32);             // <- full-row sum (pair holds k-halves)
        ell += rs;

        // ---- build P^T B-fragments in-register (half-exchange via shfl_xor 32) ----
        bf16x8 pf[4];
#pragma unroll
        for (int kc = 0; kc < 4; ++kc) {
            const f32x16& ps = (kc < 2) ? s0 : s1;
            const int bb = (kc & 1) * 8;
            uint w0 = pack2(ps[bb + 0], ps[bb + 1]);
            uint w1 = pack2(ps[bb + 2], ps[bb + 3]);
            uint w2 = pack2(ps[bb + 4], ps[bb + 5]);
            uint w3 = pack2(ps[bb + 6], ps[bb + 7]);
            uint t0 = __shfl_xor(w0, 32);
            uint t1 = __shfl_xor(w1, 32);
            uint t2 = __shfl_xor(w2, 32);
            uint t3 = __shfl_xor(w3, 32);
            uint4 u;
            u.x = h ? t2 : w0;
            u.y = h ? t3 : w1;
            u.z = h ? w2 : t0;
            u.w = h ? w3 : t1;
            pf[kc] = __builtin_bit_cast(bf16x8, u);
        }

        // ---- PV: O^T += mfma(V^T, P^T) ----
#pragma unroll
        for (int kc = 0; kc < 4; ++kc) {
            const int kk = kc * 16 + h * 8;
            const int o0 = (kk * 2 + rotv) & 127;
            const int o1 = ((kk + 4) * 2 + rotv) & 127;
#pragma unroll
            for (int dt = 0; dt < 8; ++dt) {
                const uint base = (uint)(dt * 4096 + lq * 128);
                uint2 a = *(const uint2*)(sV + base + (uint)o0);
                uint2 c2 = *(const uint2*)(sV + base + (uint)o1);
                uint4 u; u.x = a.x; u.y = a.y; u.z = c2.x; u.w = c2.y;
                acc[dt] = mfma32(__builtin_bit_cast(bf16x8, u), pf[kc], acc[dt]);
            }
        }
    }

    // ---- analytic masked tail: scores are exactly 0 there ----
    if (use_tail) {
        const int bnd = nt * 64;
        const int cnt = LKg - bnd;
        if (cnt > 0) {
            if (m < -8.f) {
                const float sf = exp2f(m);
                ell *= sf;
#pragma unroll
                for (int i = 0; i < 8; ++i) acc[i] *= sf;
                m = 0.f;
            }
            const float pt = exp2f(-m);
            ell += (float)cnt * pt;
            const float* tp = TV + b * DDg + h * 4;
#pragma unroll
            for (int dt = 0; dt < 8; ++dt) {
#pragma unroll
                for (int rg = 0; rg < 4; ++rg) {
                    float4 tv = *(const float4*)(tp + dt * 32 + rg * 8);
                    acc[dt][rg * 4 + 0] += pt * tv.x;
                    acc[dt][rg * 4 + 1] += pt * tv.y;
                    acc[dt][rg * 4 + 2] += pt * tv.z;
                    acc[dt][rg * 4 + 3] += pt * tv.w;
                }
            }
        }
    }

    // ---- epilogue: O = O^T(lane-local column) / ell ----
    const float inv = 1.f / ell;
    float* op = Og + ((size_t)(b * LQg + q)) * DDg + h * 4;
#pragma unroll
    for (int dt = 0; dt < 8; ++dt) {
#pragma unroll
        for (int rg = 0; rg < 4; ++rg) {
            float4 o;
            o.x = acc[dt][rg * 4 + 0] * inv;
            o.y = acc[dt][rg * 4 + 1] * inv;
            o.z = acc[dt][rg * 4 + 2] * inv;
            o.w = acc[dt][rg * 4 + 3] * inv;
            *(float4*)(op + dt * 32 + rg * 8) = o;
        }
    }
}

extern "C" void kernel_launch(void* const* d_in, const int* in_sizes, int n_in,
                              void* d_out, int out_size, void* d_ws, size_t ws_size,
                              hipStream_t stream) {
    const float* Q = (const float*)d_in[0];
    const float* K = (const float*)d_in[1];
    const float* V = (const float*)d_in[2];
    const int* vlen = (const int*)d_in[3];
    float* out = (float*)d_out;

    float* part = (float*)d_ws;
    float* TV = (float*)((char*)d_ws + (size_t)NBg * 16 * DDg * sizeof(float));
    const size_t need = (size_t)NBg * 16 * DDg * 4 + (size_t)NBg * DDg * 4;
    const int use_tail = (ws_size >= need) ? 1 : 0;

    if (use_tail) {
        tv_partial_k<<<dim3(16, 16), 256, 0, stream>>>(V, vlen, part);
        tv_reduce_k<<<dim3(16), 256, 0, stream>>>(part, TV);
    }
    attn_k<<<dim3(512), dim3(128), 0, stream>>>(Q, K, V, vlen, TV, out, use_tail);
}